// Round 5
// baseline (384.735 us; speedup 1.0000x reference)
//
#include <hip/hip_runtime.h>
#include <stdint.h>
#include <stddef.h>

// EdgeLearning: out[e] = W2 @ leaky(W1 @ [x[ei0[e]], x[ei1[e]], ea[e]] + b1) + b2
// bf16 MFMA (16x16x32), fp32 accumulate. Layouts per verified gfx950 mappings:
//   A frag: A[m=lane&15][k=quad*8+j]   B frag: B[n=lane&15][k=quad*8+j]
//   C/D:    col=lane&15, row=quad*4+reg
// Round 5: single change vs round 4. R4 showed VGPR_Count=64 — the allocator
// squeezed to the 64-reg occupancy step (8 waves/EU) that the 79872B LDS
// footprint caps at 4 waves/EU anyway, spilling ~11 dwords/thread/tile
// (~88 MB of scratch round-trips: FETCH 270 vs 226 clean, WRITE 244 vs 200).
// Fix: pin amdgpu_waves_per_eu(4,4) so the allocator uses the full 128-reg
// budget -> live set (~110) fits spill-free. Everything else byte-identical.

typedef short short8 __attribute__((ext_vector_type(8)));
typedef float f32x4 __attribute__((ext_vector_type(4)));

__device__ __forceinline__ short f2bf(float f) {
  union { float f; unsigned u; } v; v.f = f;
  unsigned r = (v.u + 0x7fffu + ((v.u >> 16) & 1u)) >> 16;  // RNE
  return (short)r;
}

__device__ __forceinline__ short8 cvt8(const float* __restrict__ p) {
  f32x4 a = *(const f32x4*)p;
  f32x4 b = *(const f32x4*)(p + 4);
  short8 r;
  r[0] = f2bf(a[0]); r[1] = f2bf(a[1]); r[2] = f2bf(a[2]); r[3] = f2bf(a[3]);
  r[4] = f2bf(b[0]); r[5] = f2bf(b[1]); r[6] = f2bf(b[2]); r[7] = f2bf(b[3]);
  return r;
}

// Pre-convert x (fp32) -> bf16 bits in workspace. Same RNE as cvt8, so the
// MFMA inputs are bit-identical to the fp32-gather path.
__global__ __launch_bounds__(256)
void cvt_x_kernel(const float* __restrict__ x, short* __restrict__ xb, int n8) {
  int i = blockIdx.x * blockDim.x + threadIdx.x;
  if (i < n8) *(short8*)(xb + (size_t)i * 8) = cvt8(x + (size_t)i * 8);
}

template <bool XB>
__global__
__attribute__((amdgpu_flat_work_group_size(512, 512), amdgpu_waves_per_eu(4, 4)))
void edge_mlp(const float* __restrict__ x, const short* __restrict__ xb,
              const int* __restrict__ ei, const float* __restrict__ ea,
              const float* __restrict__ W1, const float* __restrict__ b1,
              const float* __restrict__ W2, const float* __restrict__ b2,
              float* __restrict__ out, int E, int ntiles)
{
  __shared__ short  sW1[128 * 168];   // bf16 bits, padded rows (43008 B)
  __shared__ short8 sW2f[16 * 64];    // W2 frags, frag-order (16384 B)
  __shared__ short  sH[8][32 * 40];   // per-wave h chunk (20480 B) => 79872 B

  const int tid  = threadIdx.x;
  const int lane = tid & 63;
  const int wave = tid >> 6;
  const int m    = lane & 15;
  const int quad = lane >> 4;

  // Stage W1 -> LDS as bf16 (once per block; amortized over grid-stride tiles)
  for (int i = tid; i < 128 * 160; i += 512) {
    int n = i / 160;
    int k = i - n * 160;
    sW1[n * 168 + k] = f2bf(W1[i]);
  }

  // Stage W2 fragments -> LDS in frag order: frag (ot,c) for this lane is
  // B2[n=ot*16+m][k=c*32+quad*8+j]. Read back at lane*16B: conflict-free.
  if (wave == 0) {
#pragma unroll
    for (int ot = 0; ot < 4; ++ot)
#pragma unroll
      for (int c = 0; c < 4; ++c)
        sW2f[(ot * 4 + c) * 64 + lane] =
            cvt8(W2 + (size_t)(ot * 16 + m) * 128 + c * 32 + quad * 8);
  }

  float b1v[8], b2v[4];
#pragma unroll
  for (int nt = 0; nt < 8; ++nt) b1v[nt] = b1[nt * 16 + m];
#pragma unroll
  for (int ot = 0; ot < 4; ++ot) b2v[ot] = b2[ot * 16 + m];

  __syncthreads();

  short* sHw = sH[wave];

  for (int t = blockIdx.x; t < ntiles; t += gridDim.x) {
    const int ebase = t * 256 + wave * 32;

    // Gather A fragments for layer 1: mask = [x_i | x_j | ea], K = 160 (5 kt)
    short8 a1[2][5];
#pragma unroll
    for (int mt = 0; mt < 2; ++mt) {
      int e = ebase + mt * 16 + m;
      e = (e < E) ? e : (E - 1);
      const int i0 = ei[e];
      const int i1 = ei[E + e];
      if constexpr (XB) {
        const short* r0 = xb + (size_t)i0 * 64 + quad * 8;
        const short* r1 = xb + (size_t)i1 * 64 + quad * 8;
        a1[mt][0] = *(const short8*)r0;
        a1[mt][1] = *(const short8*)(r0 + 32);
        a1[mt][2] = *(const short8*)r1;
        a1[mt][3] = *(const short8*)(r1 + 32);
      } else {
        const float* r0 = x + (size_t)i0 * 64 + quad * 8;
        const float* r1 = x + (size_t)i1 * 64 + quad * 8;
        a1[mt][0] = cvt8(r0);
        a1[mt][1] = cvt8(r0 + 32);
        a1[mt][2] = cvt8(r1);
        a1[mt][3] = cvt8(r1 + 32);
      }
      a1[mt][4] = cvt8(ea + (size_t)e * 32 + quad * 8);
    }

    f32x4 acc2[2][4];
#pragma unroll
    for (int mt = 0; mt < 2; ++mt)
#pragma unroll
      for (int ot = 0; ot < 4; ++ot) {
        f32x4 z = { b2v[ot], b2v[ot], b2v[ot], b2v[ot] };
        acc2[mt][ot] = z;
      }

    // Stream h in 32-col chunks: produce 2 n-tiles, round-trip LDS, consume in layer 2
#pragma unroll
    for (int c = 0; c < 4; ++c) {
#pragma unroll
      for (int sub = 0; sub < 2; ++sub) {
        const int nt = c * 2 + sub;
        f32x4 h0 = { b1v[nt], b1v[nt], b1v[nt], b1v[nt] };
        f32x4 h1 = h0;
#pragma unroll
        for (int kt = 0; kt < 5; ++kt) {
          short8 bf = *(const short8*)&sW1[(nt * 16 + m) * 168 + kt * 32 + quad * 8];
          h0 = __builtin_amdgcn_mfma_f32_16x16x32_bf16(a1[0][kt], bf, h0, 0, 0, 0);
          h1 = __builtin_amdgcn_mfma_f32_16x16x32_bf16(a1[1][kt], bf, h1, 0, 0, 0);
        }
#pragma unroll
        for (int r = 0; r < 4; ++r) {
          float v0 = h0[r]; v0 = (v0 >= 0.0f) ? v0 : 0.01f * v0;
          float v1 = h1[r]; v1 = (v1 >= 0.0f) ? v1 : 0.01f * v1;
          sHw[(quad * 4 + r) * 40 + sub * 16 + m]      = f2bf(v0);  // m-tile 0: rows 0..15
          sHw[(16 + quad * 4 + r) * 40 + sub * 16 + m] = f2bf(v1);  // m-tile 1: rows 16..31
        }
      }
#pragma unroll
      for (int mt = 0; mt < 2; ++mt) {
        short8 a2 = *(const short8*)&sHw[(mt * 16 + m) * 40 + quad * 8];
#pragma unroll
        for (int ot = 0; ot < 4; ++ot) {
          short8 w2 = sW2f[(ot * 4 + c) * 64 + lane];
          acc2[mt][ot] = __builtin_amdgcn_mfma_f32_16x16x32_bf16(a2, w2, acc2[mt][ot], 0, 0, 0);
        }
      }
    }

    // Store: out[e][o], e = ebase + mt*16 + quad*4 + r, o = ot*16 + m
    // (byte-identical pattern to round 0's proven-clean stores)
#pragma unroll
    for (int mt = 0; mt < 2; ++mt)
#pragma unroll
      for (int ot = 0; ot < 4; ++ot)
#pragma unroll
        for (int r = 0; r < 4; ++r) {
          int er = ebase + mt * 16 + quad * 4 + r;
          if (er < E) out[(size_t)er * 64 + ot * 16 + m] = acc2[mt][ot][r];
        }
  }
}

extern "C" void kernel_launch(void* const* d_in, const int* in_sizes, int n_in,
                              void* d_out, int out_size, void* d_ws, size_t ws_size,
                              hipStream_t stream) {
  const float* x  = (const float*)d_in[0];
  const int*   ei = (const int*)d_in[1];
  const float* ea = (const float*)d_in[2];
  const float* W1 = (const float*)d_in[3];
  const float* b1 = (const float*)d_in[4];
  const float* W2 = (const float*)d_in[5];
  const float* b2 = (const float*)d_in[6];
  float* out = (float*)d_out;

  const int E  = in_sizes[1] / 2;          // edge_index is [2, E]
  const int nx = in_sizes[0];              // N_NODES * DIM_NODE floats
  const int ntiles = (E + 255) / 256;      // 256 edges per block (32 per wave)
  int grid = ntiles < 512 ? ntiles : 512;  // 2 blocks/CU x 256 CU, persistent

  short* xb = (short*)d_ws;
  const bool usebf = (d_ws != nullptr) && (ws_size >= (size_t)nx * sizeof(short))
                     && ((nx & 7) == 0);
  if (usebf) {
    const int n8 = nx / 8;
    const int cg = (n8 + 255) / 256;
    cvt_x_kernel<<<cg, 256, 0, stream>>>(x, xb, n8);
    edge_mlp<true><<<grid, 512, 0, stream>>>(x, xb, ei, ea, W1, b1, W2, b2, out, E, ntiles);
  } else {
    edge_mlp<false><<<grid, 512, 0, stream>>>(x, nullptr, ei, ea, W1, b1, W2, b2, out, E, ntiles);
  }
}

// Round 6
// 361.203 us; speedup vs baseline: 1.0651x; 1.0651x over previous
//
#include <hip/hip_runtime.h>
#include <stdint.h>
#include <stddef.h>

// EdgeLearning: out[e] = W2 @ leaky(W1 @ [x[ei0[e]], x[ei1[e]], ea[e]] + b1) + b2
// bf16 MFMA (16x16x32), fp32 accumulate. Layouts per verified gfx950 mappings:
//   A frag: A[m=lane&15][k=quad*8+j]   B frag: B[n=lane&15][k=quad*8+j]
//   C/D:    col=lane&15, row=quad*4+reg
// Round 6: the allocator pins 64 arch VGPRs (8-waves/EU step) no matter the
// declared bounds; arch live set was ~66-70 -> ~7 dword/thread/tile scratch
// spill = the symmetric +44MB FETCH/WRITE vs clean. Fix by FITTING in 64:
// b1v/b2v (12 regs) move to LDS, read per use (ds_read_b32+splat, 12/tile).
// Also: nontemporal ei/ea loads + out stores so the single-touch streams stop
// evicting the xb gather set from L2 (xb-gather fetch was 162MB for a 6.4MB
// footprint). LDS 80640B -> still 2 blocks/CU = 16 waves/CU.

typedef short short8 __attribute__((ext_vector_type(8)));
typedef float f32x4 __attribute__((ext_vector_type(4)));

__device__ __forceinline__ short f2bf(float f) {
  union { float f; unsigned u; } v; v.f = f;
  unsigned r = (v.u + 0x7fffu + ((v.u >> 16) & 1u)) >> 16;  // RNE
  return (short)r;
}

__device__ __forceinline__ short8 cvt8(const float* __restrict__ p) {
  f32x4 a = *(const f32x4*)p;
  f32x4 b = *(const f32x4*)(p + 4);
  short8 r;
  r[0] = f2bf(a[0]); r[1] = f2bf(a[1]); r[2] = f2bf(a[2]); r[3] = f2bf(a[3]);
  r[4] = f2bf(b[0]); r[5] = f2bf(b[1]); r[6] = f2bf(b[2]); r[7] = f2bf(b[3]);
  return r;
}

// Nontemporal variant for the single-touch ea stream.
__device__ __forceinline__ short8 cvt8_nt(const float* __restrict__ p) {
  f32x4 a = __builtin_nontemporal_load((const f32x4*)p);
  f32x4 b = __builtin_nontemporal_load((const f32x4*)(p + 4));
  short8 r;
  r[0] = f2bf(a[0]); r[1] = f2bf(a[1]); r[2] = f2bf(a[2]); r[3] = f2bf(a[3]);
  r[4] = f2bf(b[0]); r[5] = f2bf(b[1]); r[6] = f2bf(b[2]); r[7] = f2bf(b[3]);
  return r;
}

// Pre-convert x (fp32) -> bf16 bits in workspace. Same RNE as cvt8, so the
// MFMA inputs are bit-identical to the fp32-gather path.
__global__ __launch_bounds__(256)
void cvt_x_kernel(const float* __restrict__ x, short* __restrict__ xb, int n8) {
  int i = blockIdx.x * blockDim.x + threadIdx.x;
  if (i < n8) *(short8*)(xb + (size_t)i * 8) = cvt8(x + (size_t)i * 8);
}

template <bool XB>
__global__
__attribute__((amdgpu_flat_work_group_size(512, 512), amdgpu_waves_per_eu(4, 4)))
void edge_mlp(const float* __restrict__ x, const short* __restrict__ xb,
              const int* __restrict__ ei, const float* __restrict__ ea,
              const float* __restrict__ W1, const float* __restrict__ b1,
              const float* __restrict__ W2, const float* __restrict__ b2,
              float* __restrict__ out, int E, int ntiles)
{
  __shared__ short  sW1[128 * 168];   // bf16 bits, padded rows (43008 B)
  __shared__ short8 sW2f[16 * 64];    // W2 frags, frag-order (16384 B)
  __shared__ short  sH[8][32 * 40];   // per-wave h chunk (20480 B)
  __shared__ float  sB1[128];         // b1 (512 B)
  __shared__ float  sB2[64];          // b2 (256 B)  => total 80640 B

  const int tid  = threadIdx.x;
  const int lane = tid & 63;
  const int wave = tid >> 6;
  const int m    = lane & 15;
  const int quad = lane >> 4;

  // Stage W1 -> LDS as bf16 (once per block; amortized over grid-stride tiles)
  for (int i = tid; i < 128 * 160; i += 512) {
    int n = i / 160;
    int k = i - n * 160;
    sW1[n * 168 + k] = f2bf(W1[i]);
  }

  // Stage W2 fragments -> LDS in frag order: frag (ot,c) for this lane is
  // B2[n=ot*16+m][k=c*32+quad*8+j]. Read back at lane*16B: conflict-free.
  if (wave == 0) {
#pragma unroll
    for (int ot = 0; ot < 4; ++ot)
#pragma unroll
      for (int c = 0; c < 4; ++c)
        sW2f[(ot * 4 + c) * 64 + lane] =
            cvt8(W2 + (size_t)(ot * 16 + m) * 128 + c * 32 + quad * 8);
  }

  // Biases -> LDS (frees 12 arch VGPRs; read per use below).
  if (tid < 128) sB1[tid] = b1[tid];
  else if (tid < 192) sB2[tid - 128] = b2[tid - 128];

  __syncthreads();

  short* sHw = sH[wave];

  for (int t = blockIdx.x; t < ntiles; t += gridDim.x) {
    const int ebase = t * 256 + wave * 32;

    // Gather A fragments for layer 1: mask = [x_i | x_j | ea], K = 160 (5 kt)
    short8 a1[2][5];
#pragma unroll
    for (int mt = 0; mt < 2; ++mt) {
      int e = ebase + mt * 16 + m;
      e = (e < E) ? e : (E - 1);
      const int i0 = __builtin_nontemporal_load(&ei[e]);
      const int i1 = __builtin_nontemporal_load(&ei[E + e]);
      if constexpr (XB) {
        const short* r0 = xb + (size_t)i0 * 64 + quad * 8;
        const short* r1 = xb + (size_t)i1 * 64 + quad * 8;
        a1[mt][0] = *(const short8*)r0;
        a1[mt][1] = *(const short8*)(r0 + 32);
        a1[mt][2] = *(const short8*)r1;
        a1[mt][3] = *(const short8*)(r1 + 32);
      } else {
        const float* r0 = x + (size_t)i0 * 64 + quad * 8;
        const float* r1 = x + (size_t)i1 * 64 + quad * 8;
        a1[mt][0] = cvt8(r0);
        a1[mt][1] = cvt8(r0 + 32);
        a1[mt][2] = cvt8(r1);
        a1[mt][3] = cvt8(r1 + 32);
      }
      a1[mt][4] = cvt8_nt(ea + (size_t)e * 32 + quad * 8);
    }

    f32x4 acc2[2][4];
#pragma unroll
    for (int mt = 0; mt < 2; ++mt)
#pragma unroll
      for (int ot = 0; ot < 4; ++ot) {
        const float b2o = sB2[ot * 16 + m];
        f32x4 z = { b2o, b2o, b2o, b2o };
        acc2[mt][ot] = z;
      }

    // Stream h in 32-col chunks: produce 2 n-tiles, round-trip LDS, consume in layer 2
#pragma unroll
    for (int c = 0; c < 4; ++c) {
#pragma unroll
      for (int sub = 0; sub < 2; ++sub) {
        const int nt = c * 2 + sub;
        const float b1n = sB1[nt * 16 + m];
        f32x4 h0 = { b1n, b1n, b1n, b1n };
        f32x4 h1 = h0;
#pragma unroll
        for (int kt = 0; kt < 5; ++kt) {
          short8 bf = *(const short8*)&sW1[(nt * 16 + m) * 168 + kt * 32 + quad * 8];
          h0 = __builtin_amdgcn_mfma_f32_16x16x32_bf16(a1[0][kt], bf, h0, 0, 0, 0);
          h1 = __builtin_amdgcn_mfma_f32_16x16x32_bf16(a1[1][kt], bf, h1, 0, 0, 0);
        }
#pragma unroll
        for (int r = 0; r < 4; ++r) {
          float v0 = h0[r]; v0 = (v0 >= 0.0f) ? v0 : 0.01f * v0;
          float v1 = h1[r]; v1 = (v1 >= 0.0f) ? v1 : 0.01f * v1;
          sHw[(quad * 4 + r) * 40 + sub * 16 + m]      = f2bf(v0);  // m-tile 0: rows 0..15
          sHw[(16 + quad * 4 + r) * 40 + sub * 16 + m] = f2bf(v1);  // m-tile 1: rows 16..31
        }
      }
#pragma unroll
      for (int mt = 0; mt < 2; ++mt) {
        short8 a2 = *(const short8*)&sHw[(mt * 16 + m) * 40 + quad * 8];
#pragma unroll
        for (int ot = 0; ot < 4; ++ot) {
          short8 w2 = sW2f[(ot * 4 + c) * 64 + lane];
          acc2[mt][ot] = __builtin_amdgcn_mfma_f32_16x16x32_bf16(a2, w2, acc2[mt][ot], 0, 0, 0);
        }
      }
    }

    // Store: out[e][o], e = ebase + mt*16 + quad*4 + r, o = ot*16 + m
    // Same addressing as round 0; nontemporal (single-touch stream).
#pragma unroll
    for (int mt = 0; mt < 2; ++mt)
#pragma unroll
      for (int ot = 0; ot < 4; ++ot)
#pragma unroll
        for (int r = 0; r < 4; ++r) {
          int er = ebase + mt * 16 + quad * 4 + r;
          if (er < E)
            __builtin_nontemporal_store(acc2[mt][ot][r],
                                        &out[(size_t)er * 64 + ot * 16 + m]);
        }
  }
}

extern "C" void kernel_launch(void* const* d_in, const int* in_sizes, int n_in,
                              void* d_out, int out_size, void* d_ws, size_t ws_size,
                              hipStream_t stream) {
  const float* x  = (const float*)d_in[0];
  const int*   ei = (const int*)d_in[1];
  const float* ea = (const float*)d_in[2];
  const float* W1 = (const float*)d_in[3];
  const float* b1 = (const float*)d_in[4];
  const float* W2 = (const float*)d_in[5];
  const float* b2 = (const float*)d_in[6];
  float* out = (float*)d_out;

  const int E  = in_sizes[1] / 2;          // edge_index is [2, E]
  const int nx = in_sizes[0];              // N_NODES * DIM_NODE floats
  const int ntiles = (E + 255) / 256;      // 256 edges per block (32 per wave)
  int grid = ntiles < 512 ? ntiles : 512;  // 2 blocks/CU x 256 CU, persistent

  short* xb = (short*)d_ws;
  const bool usebf = (d_ws != nullptr) && (ws_size >= (size_t)nx * sizeof(short))
                     && ((nx & 7) == 0);
  if (usebf) {
    const int n8 = nx / 8;
    const int cg = (n8 + 255) / 256;
    cvt_x_kernel<<<cg, 256, 0, stream>>>(x, xb, n8);
    edge_mlp<true><<<grid, 512, 0, stream>>>(x, xb, ei, ea, W1, b1, W2, b2, out, E, ntiles);
  } else {
    edge_mlp<false><<<grid, 512, 0, stream>>>(x, nullptr, ei, ea, W1, b1, W2, b2, out, E, ntiles);
  }
}

// Round 7
// 355.048 us; speedup vs baseline: 1.0836x; 1.0173x over previous
//
#include <hip/hip_runtime.h>
#include <stdint.h>
#include <stddef.h>

// EdgeLearning: out[e] = W2 @ leaky(W1 @ [x[ei0[e]], x[ei1[e]], ea[e]] + b1) + b2
// bf16 MFMA (16x16x32), fp32 accumulate. Layouts per verified gfx950 mappings:
//   A frag: A[m=lane&15][k=quad*8+j]   B frag: B[n=lane&15][k=quad*8+j]
//   C/D:    col=lane&15, row=quad*4+reg
// Round 7 (on top of R6's 128us): two changes.
//  (1) Layer-2 operands swapped (R2 mechanics, now spill-free): D[o][edge],
//      lane holds 4 consecutive out-floats -> 8x dwordx4 NT stores per tile
//      instead of 32 scalar NT dwords (full 64B lines per inst). Target:
//      WRITE 252->205 MB (the +47 was NT sub-line granule flushes).
//  (2) ea+ei prefetched one tile ahead (~35 regs, VGPR 56->~85): the only
//      HBM-latency per-tile load (ea ~900cyc) completes under the previous
//      tile's compute. xb gathers stay at tile top (L2-resident ~300cyc).
// Spill tell-tale: symmetric FETCH/WRITE inflation; clean = FETCH ~107 MB.

typedef short short8 __attribute__((ext_vector_type(8)));
typedef float f32x4 __attribute__((ext_vector_type(4)));

__device__ __forceinline__ short f2bf(float f) {
  union { float f; unsigned u; } v; v.f = f;
  unsigned r = (v.u + 0x7fffu + ((v.u >> 16) & 1u)) >> 16;  // RNE
  return (short)r;
}

__device__ __forceinline__ short8 cvt8(const float* __restrict__ p) {
  f32x4 a = *(const f32x4*)p;
  f32x4 b = *(const f32x4*)(p + 4);
  short8 r;
  r[0] = f2bf(a[0]); r[1] = f2bf(a[1]); r[2] = f2bf(a[2]); r[3] = f2bf(a[3]);
  r[4] = f2bf(b[0]); r[5] = f2bf(b[1]); r[6] = f2bf(b[2]); r[7] = f2bf(b[3]);
  return r;
}

// Pre-convert x (fp32) -> bf16 bits in workspace. Same RNE as cvt8, so the
// MFMA inputs are bit-identical to the fp32-gather path.
__global__ __launch_bounds__(256)
void cvt_x_kernel(const float* __restrict__ x, short* __restrict__ xb, int n8) {
  int i = blockIdx.x * blockDim.x + threadIdx.x;
  if (i < n8) *(short8*)(xb + (size_t)i * 8) = cvt8(x + (size_t)i * 8);
}

template <bool XB>
__global__
__attribute__((amdgpu_flat_work_group_size(512, 512), amdgpu_waves_per_eu(4, 4)))
void edge_mlp(const float* __restrict__ x, const short* __restrict__ xb,
              const int* __restrict__ ei, const float* __restrict__ ea,
              const float* __restrict__ W1, const float* __restrict__ b1,
              const float* __restrict__ W2, const float* __restrict__ b2,
              float* __restrict__ out, int E, int ntiles)
{
  __shared__ short  sW1[128 * 168];   // bf16 bits, padded rows (43008 B)
  __shared__ short8 sW2f[16 * 64];    // W2 frags, frag-order (16384 B)
  __shared__ short  sH[8][32 * 40];   // per-wave h chunk (20480 B)
  __shared__ float  sB1[128];         // b1 (512 B)
  __shared__ float  sB2[64];          // b2 (256 B)  => total 80640 B

  const int tid  = threadIdx.x;
  const int lane = tid & 63;
  const int wave = tid >> 6;
  const int m    = lane & 15;
  const int quad = lane >> 4;

  // Stage W1 -> LDS as bf16 (once per block; amortized over grid-stride tiles)
  for (int i = tid; i < 128 * 160; i += 512) {
    int n = i / 160;
    int k = i - n * 160;
    sW1[n * 168 + k] = f2bf(W1[i]);
  }

  // Stage W2 fragments -> LDS in frag order: frag (ot,c) for this lane is
  // W2[o=ot*16+m][k=c*32+quad*8+j]. Read back at lane*16B: conflict-free.
  // Used as the A-operand of the swapped layer-2 MFMA (same lane mapping).
  if (wave == 0) {
#pragma unroll
    for (int ot = 0; ot < 4; ++ot)
#pragma unroll
      for (int c = 0; c < 4; ++c)
        sW2f[(ot * 4 + c) * 64 + lane] =
            cvt8(W2 + (size_t)(ot * 16 + m) * 128 + c * 32 + quad * 8);
  }

  // Biases -> LDS (keeps arch-VGPR live set small; read per use below).
  if (tid < 128) sB1[tid] = b1[tid];
  else if (tid < 192) sB2[tid - 128] = b2[tid - 128];

  __syncthreads();

  short* sHw = sH[wave];

  // Compute + store for one tile, given ready a1 fragments. Swapped layer 2:
  // D[row=o][col=edge] -> dense dwordx4 NT stores.
  auto compute_store = [&](int tt, const short8 (&a1)[2][5]) {
    const int ebase = tt * 256 + wave * 32;

    f32x4 acc2[2][4];
#pragma unroll
    for (int ot = 0; ot < 4; ++ot) {
      f32x4 bz = *(const f32x4*)&sB2[ot * 16 + quad * 4];
      acc2[0][ot] = bz;
      acc2[1][ot] = bz;
    }

    // Stream h in 32-col chunks: 2 n-tiles -> LDS roundtrip -> layer 2.
#pragma unroll
    for (int c = 0; c < 4; ++c) {
#pragma unroll
      for (int sub = 0; sub < 2; ++sub) {
        const int nt = c * 2 + sub;
        const float b1n = sB1[nt * 16 + m];
        f32x4 h0 = { b1n, b1n, b1n, b1n };
        f32x4 h1 = h0;
#pragma unroll
        for (int kt = 0; kt < 5; ++kt) {
          short8 bf = *(const short8*)&sW1[(nt * 16 + m) * 168 + kt * 32 + quad * 8];
          h0 = __builtin_amdgcn_mfma_f32_16x16x32_bf16(a1[0][kt], bf, h0, 0, 0, 0);
          h1 = __builtin_amdgcn_mfma_f32_16x16x32_bf16(a1[1][kt], bf, h1, 0, 0, 0);
        }
#pragma unroll
        for (int r = 0; r < 4; ++r) {
          float v0 = h0[r]; v0 = (v0 >= 0.0f) ? v0 : 0.01f * v0;
          float v1 = h1[r]; v1 = (v1 >= 0.0f) ? v1 : 0.01f * v1;
          sHw[(quad * 4 + r) * 40 + sub * 16 + m]      = f2bf(v0);  // edges 0..15
          sHw[(16 + quad * 4 + r) * 40 + sub * 16 + m] = f2bf(v1);  // edges 16..31
        }
      }
#pragma unroll
      for (int mt = 0; mt < 2; ++mt) {
        short8 a2 = *(const short8*)&sHw[(mt * 16 + m) * 40 + quad * 8];
        // SWAPPED: D[row=o][col=edge] = sum_k W2[o][k] * h[edge][k]
#pragma unroll
        for (int ot = 0; ot < 4; ++ot) {
          short8 w2 = sW2f[(ot * 4 + c) * 64 + lane];
          acc2[mt][ot] = __builtin_amdgcn_mfma_f32_16x16x32_bf16(w2, a2, acc2[mt][ot], 0, 0, 0);
        }
      }
    }

    // Dense stores: lane (quad,m) holds out[edge=ebase+mt*16+m][ot*16+quad*4+{0..3}]
    // -> one dwordx4 per (mt,ot); a wave's 4 ot-stores cover 16 edges x 256B fully.
#pragma unroll
    for (int mt = 0; mt < 2; ++mt) {
      int er = ebase + mt * 16 + m;
      if (er < E) {
        float* po = out + (size_t)er * 64 + quad * 4;
#pragma unroll
        for (int ot = 0; ot < 4; ++ot)
          __builtin_nontemporal_store(acc2[mt][ot], (f32x4*)(po + ot * 16));
      }
    }
  };

  if constexpr (!XB) {
    // Fallback (no workspace): unpipelined fp32 gather, same compute/store.
    for (int t = blockIdx.x; t < ntiles; t += gridDim.x) {
      const int ebase = t * 256 + wave * 32;
      short8 a1[2][5];
#pragma unroll
      for (int mt = 0; mt < 2; ++mt) {
        int e = ebase + mt * 16 + m;
        e = (e < E) ? e : (E - 1);
        const int i0 = ei[e];
        const int i1 = ei[E + e];
        const float* r0 = x + (size_t)i0 * 64 + quad * 8;
        const float* r1 = x + (size_t)i1 * 64 + quad * 8;
        a1[mt][0] = cvt8(r0);
        a1[mt][1] = cvt8(r0 + 32);
        a1[mt][2] = cvt8(r1);
        a1[mt][3] = cvt8(r1 + 32);
        a1[mt][4] = cvt8(ea + (size_t)e * 32 + quad * 8);
      }
      compute_store(t, a1);
    }
  } else {
    // Pipelined: ei + ea for tile t+grid are in flight during tile t's compute.
    const int g1 = gridDim.x;

    auto ld_idx = [&](int tt, int (&idx)[2][2]) {
      const int eb = tt * 256 + wave * 32;
#pragma unroll
      for (int mt = 0; mt < 2; ++mt) {
        int e = eb + mt * 16 + m;
        e = (e < E) ? e : (E - 1);
        idx[mt][0] = __builtin_nontemporal_load(&ei[e]);
        idx[mt][1] = __builtin_nontemporal_load(&ei[E + e]);
      }
    };
    auto ld_ea = [&](int tt, f32x4 (&er)[2][2]) {
      const int eb = tt * 256 + wave * 32;
#pragma unroll
      for (int mt = 0; mt < 2; ++mt) {
        int e = eb + mt * 16 + m;
        e = (e < E) ? e : (E - 1);
        const float* pe = ea + (size_t)e * 32 + quad * 8;
        er[mt][0] = __builtin_nontemporal_load((const f32x4*)pe);
        er[mt][1] = __builtin_nontemporal_load((const f32x4*)(pe + 4));
      }
    };

    int t = blockIdx.x;
    if (t >= ntiles) return;

    int   idxC[2][2];
    f32x4 eaC[2][2];
    ld_idx(t, idxC);
    ld_ea(t, eaC);

    for (; t < ntiles; t += g1) {
      // Issue this tile's xb gathers (L2-resident, ~300cyc; hidden by the
      // ea-convert + early layer-1 MFMAs below).
      short8 a1[2][5];
#pragma unroll
      for (int mt = 0; mt < 2; ++mt) {
        const short* r0 = xb + (size_t)idxC[mt][0] * 64 + quad * 8;
        const short* r1 = xb + (size_t)idxC[mt][1] * 64 + quad * 8;
        a1[mt][0] = *(const short8*)r0;
        a1[mt][1] = *(const short8*)(r0 + 32);
        a1[mt][2] = *(const short8*)r1;
        a1[mt][3] = *(const short8*)(r1 + 32);
      }

      // Prefetch next tile's ei + ea (in flight across this tile's compute).
      const int tn = (t + g1 < ntiles) ? (t + g1) : t;
      int   idxN[2][2];
      f32x4 eaN[2][2];
      ld_idx(tn, idxN);
      ld_ea(tn, eaN);

      // Convert this tile's ea (loaded last iteration) -> bf16 fragment.
#pragma unroll
      for (int mt = 0; mt < 2; ++mt) {
        short8 r;
        r[0] = f2bf(eaC[mt][0][0]); r[1] = f2bf(eaC[mt][0][1]);
        r[2] = f2bf(eaC[mt][0][2]); r[3] = f2bf(eaC[mt][0][3]);
        r[4] = f2bf(eaC[mt][1][0]); r[5] = f2bf(eaC[mt][1][1]);
        r[6] = f2bf(eaC[mt][1][2]); r[7] = f2bf(eaC[mt][1][3]);
        a1[mt][4] = r;
      }

      compute_store(t, a1);

      // Rotate pipeline registers.
#pragma unroll
      for (int mt = 0; mt < 2; ++mt) {
        idxC[mt][0] = idxN[mt][0];
        idxC[mt][1] = idxN[mt][1];
        eaC[mt][0]  = eaN[mt][0];
        eaC[mt][1]  = eaN[mt][1];
      }
    }
  }
}

extern "C" void kernel_launch(void* const* d_in, const int* in_sizes, int n_in,
                              void* d_out, int out_size, void* d_ws, size_t ws_size,
                              hipStream_t stream) {
  const float* x  = (const float*)d_in[0];
  const int*   ei = (const int*)d_in[1];
  const float* ea = (const float*)d_in[2];
  const float* W1 = (const float*)d_in[3];
  const float* b1 = (const float*)d_in[4];
  const float* W2 = (const float*)d_in[5];
  const float* b2 = (const float*)d_in[6];
  float* out = (float*)d_out;

  const int E  = in_sizes[1] / 2;          // edge_index is [2, E]
  const int nx = in_sizes[0];              // N_NODES * DIM_NODE floats
  const int ntiles = (E + 255) / 256;      // 256 edges per block (32 per wave)
  int grid = ntiles < 512 ? ntiles : 512;  // 2 blocks/CU x 256 CU, persistent

  short* xb = (short*)d_ws;
  const bool usebf = (d_ws != nullptr) && (ws_size >= (size_t)nx * sizeof(short))
                     && ((nx & 7) == 0);
  if (usebf) {
    const int n8 = nx / 8;
    const int cg = (n8 + 255) / 256;
    cvt_x_kernel<<<cg, 256, 0, stream>>>(x, xb, n8);
    edge_mlp<true><<<grid, 512, 0, stream>>>(x, xb, ei, ea, W1, b1, W2, b2, out, E, ntiles);
  } else {
    edge_mlp<false><<<grid, 512, 0, stream>>>(x, nullptr, ei, ea, W1, b1, W2, b2, out, E, ntiles);
  }
}